// Round 7
// baseline (418.664 us; speedup 1.0000x reference)
//
#include <hip/hip_runtime.h>
#include <hip/hip_bf16.h>
#include <cmath>

typedef __bf16 bf16_t;
typedef __bf16 bf16x4 __attribute__((ext_vector_type(4)));
typedef __bf16 bf16x8 __attribute__((ext_vector_type(8)));
typedef float  f32x4  __attribute__((ext_vector_type(4)));

// ---------------------------------------------------------------------------
// async global->LDS, 16B per lane (LDS dest = wave-uniform base + lane*16)
// ---------------------------------------------------------------------------
__device__ __forceinline__ void gld_lds16(const bf16_t* g, bf16_t* l) {
    __builtin_amdgcn_global_load_lds(
        (const __attribute__((address_space(1))) void*)g,
        (__attribute__((address_space(3))) void*)l,
        16, 0, 0);
}

// ---------------------------------------------------------------------------
// prep: ONE launch for x-cast + 6 weight transposes + qk-bias pack
// ---------------------------------------------------------------------------
struct PrepArgs {
    const float* w[6]; bf16_t* wt[6];
    int K[6], N[6], start[6];
    const float* x; bf16_t* xb; int castStart;
    const float* bq; const float* bk; float* bqkv; int biasStart;
};

__global__ __launch_bounds__(256) void prep(PrepArgs pa) {
    __shared__ float tile[32][33];
    const int bid = blockIdx.x, t = threadIdx.x;
    if (bid < pa.castStart) {
        int mi = 0;
#pragma unroll
        for (int i = 1; i < 6; i++) if (bid >= pa.start[i]) mi = i;
        const int tt  = bid - pa.start[mi];
        const int nbx = pa.N[mi] >> 5;
        const int n0 = (tt % nbx) * 32, k0 = (tt / nbx) * 32;
        const float* in = pa.w[mi];
        bf16_t* out = pa.wt[mi];
        const int K = pa.K[mi], N = pa.N[mi];
        const int tx = t & 31, ty = t >> 5;
#pragma unroll
        for (int i = 0; i < 4; i++) {
            int kk = ty + i * 8;
            tile[kk][tx] = in[(size_t)(k0 + kk) * N + n0 + tx];
        }
        __syncthreads();
#pragma unroll
        for (int i = 0; i < 4; i++) {
            int nn = ty + i * 8;
            out[(size_t)(n0 + nn) * K + k0 + tx] = (bf16_t)tile[tx][nn];
        }
    } else if (bid < pa.biasStart) {
        int i = (bid - pa.castStart) * 256 + t;
        f32x4 v = ((const f32x4*)pa.x)[i];
        bf16x4 o;
        o[0] = (bf16_t)v[0]; o[1] = (bf16_t)v[1]; o[2] = (bf16_t)v[2]; o[3] = (bf16_t)v[3];
        ((bf16x4*)pa.xb)[i] = o;
    } else {
#pragma unroll
        for (int j = 0; j < 8; j++) {
            int idx = t * 8 + j;
            pa.bqkv[idx] = idx < 1024 ? pa.bq[idx] : pa.bk[idx - 1024];
        }
    }
}

// ---------------------------------------------------------------------------
// GEMM descriptor + core:  C[M][N] = A[M][K]*Bt[N][K]^T + bias (+relu)
// Tile (MT*32)x128, BK=64 as two 32-halves, 4 waves (2x2).
// kh = K-split index (partials at Cf + kh*M*N, bias only in kh==0).
// scale_cols/scale: pre-fold softmax scale into Q columns at QK epilogue.
// ---------------------------------------------------------------------------
struct GemmDesc {
    const bf16_t* A; const bf16_t* Bt; const float* bias;
    float* Cf; bf16_t* Cb;
    int M, N, lda, Kloc, relu, nbn, bias_row;
    long bt_bstride, c_bstride;
    int scale_cols; float scale;
};

template<int MT>
__device__ __forceinline__ void gemm_core(const GemmDesc& d, int bidx, int batch,
                                          int kh, bf16_t* As, bf16_t* Bs) {
    constexpr int TM = MT * 32;
    const int tid  = threadIdx.x;
    const int lane = tid & 63;
    const int wave = tid >> 6;
    const int wm = wave & 1, wn = wave >> 1;

    const int span  = 8 * d.nbn;            // nbm % 8 == 0 for all launches
    const int group = bidx / span;
    const int rem   = bidx % span;
    const int bm    = group * 8 + (rem & 7);
    const int bn    = rem >> 3;

    const bf16_t* Bt_b = d.Bt + (size_t)batch * d.bt_bstride;
    float*  Cf_b = d.Cf ? d.Cf + (size_t)batch * d.c_bstride + (size_t)kh * d.M * d.N : nullptr;
    bf16_t* Cb_b = d.Cb ? d.Cb + (size_t)batch * d.c_bstride : nullptr;
    const int koff = kh * d.Kloc;

    const int r4 = tid >> 2;
    const int kc = (tid & 3) * 8;
    const bf16_t* Ag = d.A  + (size_t)(bm * TM  + r4) * d.lda + koff + kc;
    const bf16_t* Bg = Bt_b + (size_t)(bn * 128 + r4) * d.lda + koff + kc;

    f32x4 acc[MT][4] = {};
    const int mrow = lane & 15;
    const int q8   = (lane >> 4) * 8;

    for (int k0 = 0; k0 < d.Kloc; k0 += 64) {
        __syncthreads();
#pragma unroll
        for (int hh = 0; hh < 2; hh++) {
#pragma unroll
            for (int i = 0; i < MT / 2; i++)
                gld_lds16(Ag + (size_t)(i * 64) * d.lda + k0 + hh * 32,
                          As + hh * (TM * 32) + i * 64 * 32 + tid * 8);
            gld_lds16(Bg + k0 + hh * 32,                      Bs + hh * 4096 + tid * 8);
            gld_lds16(Bg + (size_t)64 * d.lda + k0 + hh * 32, Bs + hh * 4096 + 64 * 32 + tid * 8);
        }
        __syncthreads();

#pragma unroll
        for (int hh = 0; hh < 2; hh++) {
            bf16x8 af[MT], bfr[4];
#pragma unroll
            for (int mt = 0; mt < MT; mt++)
                af[mt] = *(const bf16x8*)(As + hh * (TM * 32) +
                                          (wm * (MT * 16) + mt * 16 + mrow) * 32 + q8);
#pragma unroll
            for (int nt = 0; nt < 4; nt++)
                bfr[nt] = *(const bf16x8*)(Bs + hh * 4096 +
                                           (wn * 64 + nt * 16 + mrow) * 32 + q8);
#pragma unroll
            for (int mt = 0; mt < MT; mt++)
#pragma unroll
                for (int nt = 0; nt < 4; nt++)
                    acc[mt][nt] = __builtin_amdgcn_mfma_f32_16x16x32_bf16(
                        af[mt], bfr[nt], acc[mt][nt], 0, 0, 0);
        }
    }

    const int rq = (lane >> 4) * 4;
#pragma unroll
    for (int mt = 0; mt < MT; mt++) {
        int row0 = bm * TM + wm * (MT * 16) + mt * 16 + rq;
#pragma unroll
        for (int nt = 0; nt < 4; nt++) {
            int col = bn * 128 + wn * 64 + nt * 16 + mrow;
            float bvc = (d.bias && kh == 0 && !d.bias_row) ? d.bias[col] : 0.f;
            float sc = (col < d.scale_cols) ? d.scale : 1.f;
#pragma unroll
            for (int r = 0; r < 4; r++) {
                float bb = (d.bias && kh == 0 && d.bias_row) ? d.bias[row0 + r] : bvc;
                float v = acc[mt][nt][r] + bb;
                if (d.relu) v = fmaxf(v, 0.f);
                v *= sc;
                size_t idx = (size_t)(row0 + r) * d.N + col;
                if (Cf_b) Cf_b[idx] = v;
                if (Cb_b) Cb_b[idx] = (bf16_t)v;
            }
        }
    }
}

template<int MT>
__global__ __launch_bounds__(256) void gemm_bt(GemmDesc d) {
    __shared__ __attribute__((aligned(16))) bf16_t As[2 * MT * 32 * 32];
    __shared__ __attribute__((aligned(16))) bf16_t Bs[2 * 128 * 32];
    gemm_core<MT>(d, blockIdx.x, blockIdx.y, blockIdx.z, As, Bs);
}

// Two independent MT=4 GEMMs in one launch (overlaps ramps, kills a graph gap).
// d1 has nblocks1 = nbm1*nbn1 blocks per batch, nbatch1 batches.
__global__ __launch_bounds__(256) void gemm_dual(GemmDesc d0, int nblocks0,
                                                 GemmDesc d1, int nblocks1) {
    __shared__ __attribute__((aligned(16))) bf16_t As[2 * 128 * 32];
    __shared__ __attribute__((aligned(16))) bf16_t Bs[2 * 128 * 32];
    const int bid = blockIdx.x;
    if (bid < nblocks0) {
        gemm_core<4>(d0, bid, 0, 0, As, Bs);
    } else {
        int b2 = bid - nblocks0;
        gemm_core<4>(d1, b2 % nblocks1, b2 / nblocks1, 0, As, Bs);
    }
}

// ---------------------------------------------------------------------------
// MFMA flash attention (bf16, no-max softmax, MFMA row-sum).
// r7: 128-row Q tile, 8 waves (512 threads) -> K/V staging + barriers per CU
// halve vs the 64-row version; MFMA per CU unchanged.
// QKb [B*S][2048]: q (pre-scaled by 0.125*log2e) at h*64, k at 1024+h*64.
// Vt [B][1024][2048]: row hd, col s.
// LDS: QPs arena = Q staging ([2][128][32], 8192 els) then reused as
// Ps[128][72]. Ks/Vs [2][64*32], half stride 2048 els.
// ---------------------------------------------------------------------------
__global__ __launch_bounds__(512) void flash_attn_mfma(
    const bf16_t* __restrict__ QKb,
    const bf16_t* __restrict__ Vtg,
    bf16_t* __restrict__ Outb) {
    __shared__ __attribute__((aligned(16))) bf16_t QPs[128 * 72];  // 18 KB
    __shared__ __attribute__((aligned(16))) bf16_t Ks[2][64 * 32]; //  8 KB
    __shared__ __attribute__((aligned(16))) bf16_t Vs[2][64 * 32]; //  8 KB
    const int t = threadIdx.x;            // 0..511
    const int lane = t & 63, wave = t >> 6;  // wave 0..7
    const int g = lane >> 4, cl = lane & 15;
    const int b = blockIdx.z, h = blockIdx.y, q0 = blockIdx.x * 128;
    const int RS = 2048;
    const bf16_t* Qg = QKb + (size_t)(b * 2048 + q0) * RS + h * 64;
    const bf16_t* Kg = QKb + (size_t)(b * 2048) * RS + 1024 + h * 64;
    const bf16_t* Vg = Vtg + ((size_t)b * 1024 + h * 64) * 2048;

    // stage Q [2][128][32]: issue i covers half i (512 thr x 8 els = 4096)
    {
        int qr = t >> 2, qc = (t & 3) * 8;
        gld_lds16(Qg + (size_t)qr * RS + qc,      QPs + t * 8);
        gld_lds16(Qg + (size_t)qr * RS + 32 + qc, QPs + 4096 + t * 8);
    }
    // K/V staging map: one issue covers both halves (t<256 -> half0)
    const int kr = (t & 255) >> 2;
    const int kc = (t & 3) * 8;
    const int khf = (t >> 8) * 32;

    f32x4 Oacc[4] = {};
    f32x4 Lacc = {};
    bf16x8 ones;
#pragma unroll
    for (int j = 0; j < 8; j++) ones[j] = (bf16_t)1.0f;

    const int qrow_s = (wave * 16 + cl) * 32 + g * 8;
    const int prow_w = (wave * 16 + cl) * 72;

    // hoist loop-invariant Q fragments (frees QPs arena for Ps)
    __syncthreads();    // Q staging drained (barrier implies vmcnt(0))
    const bf16x8 bq0 = *(const bf16x8*)(QPs + qrow_s);
    const bf16x8 bq1 = *(const bf16x8*)(QPs + 4096 + qrow_s);
    // loop-entry barrier guarantees all waves' Q reads precede Ps writes

    for (int kt = 0; kt < 2048; kt += 64) {
        __syncthreads();   // prev iter's Ks/Vs/Ps reads done before overwrite
        gld_lds16(Kg + (size_t)(kt + kr) * RS + khf + kc,  (bf16_t*)Ks + t * 8);
        gld_lds16(Vg + (size_t)kr * 2048 + kt + khf + kc,  (bf16_t*)Vs + t * 8);
        __syncthreads();   // staging drained

        // S^T = K * Q^T : D[key_local][q_local]  (Q pre-scaled)
        f32x4 Sacc[4] = {};
#pragma unroll
        for (int ks = 0; ks < 2; ks++) {
            const bf16x8 bq = ks ? bq1 : bq0;
#pragma unroll
            for (int mt = 0; mt < 4; mt++) {
                bf16x8 ak = *(const bf16x8*)(&Ks[ks][(mt * 16 + cl) * 32 + g * 8]);
                Sacc[mt] = __builtin_amdgcn_mfma_f32_16x16x32_bf16(ak, bq, Sacc[mt], 0, 0, 0);
            }
        }

        // P = exp2(S')   frag: key = mt*16+g*4+r, q = cl -> Ps[q][key]
#pragma unroll
        for (int mt = 0; mt < 4; mt++) {
            bf16x4 p4;
#pragma unroll
            for (int r = 0; r < 4; r++)
                p4[r] = (bf16_t)__builtin_amdgcn_exp2f(Sacc[mt][r]);
            *(bf16x4*)(QPs + prow_w + mt * 16 + g * 4) = p4;
        }
        // intra-wave LDS RAW only (each wave reads back its own 16 P-rows)

        // O += P * V ; L += P * 1
#pragma unroll
        for (int ks = 0; ks < 2; ks++) {
            bf16x8 ap = *(const bf16x8*)(QPs + prow_w + ks * 32 + g * 8);
            Lacc = __builtin_amdgcn_mfma_f32_16x16x32_bf16(ap, ones, Lacc, 0, 0, 0);
#pragma unroll
            for (int nt = 0; nt < 4; nt++) {
                bf16x8 bv = *(const bf16x8*)(&Vs[ks][(nt * 16 + cl) * 32 + g * 8]);
                Oacc[nt] = __builtin_amdgcn_mfma_f32_16x16x32_bf16(ap, bv, Oacc[nt], 0, 0, 0);
            }
        }
    }

    // epilogue: O /= L. row q_local = g*4+r, col d = nt*16+cl
#pragma unroll
    for (int r = 0; r < 4; r++) {
        float inv = 1.f / Lacc[r];
        int qrow = q0 + wave * 16 + g * 4 + r;
        size_t base = (size_t)(b * 2048 + qrow) * 1024 + h * 64;
#pragma unroll
        for (int nt = 0; nt < 4; nt++)
            Outb[base + nt * 16 + cl] = (bf16_t)(Oacc[nt][r] * inv);
    }
}

// ---------------------------------------------------------------------------
// out = LN(a + p0 + p1) * g + be ; p1/outb nullable. one block/row, D=1024
// ---------------------------------------------------------------------------
__global__ __launch_bounds__(256) void resid_ln3(const float* __restrict__ a,
                                                 const float* __restrict__ p0,
                                                 const float* __restrict__ p1,
                                                 const float* __restrict__ g,
                                                 const float* __restrict__ be,
                                                 float* __restrict__ outf,
                                                 bf16_t* __restrict__ outb) {
    const int row = blockIdx.x, t = threadIdx.x;
    const size_t base = (size_t)row * 1024;
    f32x4 v = ((const f32x4*)(a + base))[t] + ((const f32x4*)(p0 + base))[t];
    if (p1) v += ((const f32x4*)(p1 + base))[t];
    float sum = v[0] + v[1] + v[2] + v[3];
    float sq  = v[0] * v[0] + v[1] * v[1] + v[2] * v[2] + v[3] * v[3];
#pragma unroll
    for (int o = 1; o < 64; o <<= 1) {
        sum += __shfl_xor(sum, o);
        sq  += __shfl_xor(sq, o);
    }
    __shared__ float red[8];
    int wave = t >> 6, lane = t & 63;
    if (lane == 0) { red[wave] = sum; red[4 + wave] = sq; }
    __syncthreads();
    sum = red[0] + red[1] + red[2] + red[3];
    sq  = red[4] + red[5] + red[6] + red[7];
    float mu  = sum * (1.f / 1024.f);
    float var = sq * (1.f / 1024.f) - mu * mu;
    float rs  = rsqrtf(var + 1e-6f);
    f32x4 g4 = ((const f32x4*)g)[t];
    f32x4 b4 = ((const f32x4*)be)[t];
    f32x4 o = (v - mu) * rs * g4 + b4;
    ((f32x4*)(outf + base))[t] = o;
    if (outb) {
        bf16x4 ob;
        ob[0] = (bf16_t)o[0]; ob[1] = (bf16_t)o[1]; ob[2] = (bf16_t)o[2]; ob[3] = (bf16_t)o[3];
        ((bf16x4*)(outb + base))[t] = ob;
    }
}

// ---------------------------------------------------------------------------
extern "C" void kernel_launch(void* const* d_in, const int* in_sizes, int n_in,
                              void* d_out, int out_size, void* d_ws, size_t ws_size,
                              hipStream_t stream) {
    (void)in_sizes; (void)n_in; (void)out_size; (void)ws_size;
    const float* x   = (const float*)d_in[0];
    const float* wq  = (const float*)d_in[1];
    const float* bq  = (const float*)d_in[2];
    const float* wk  = (const float*)d_in[3];
    const float* bk  = (const float*)d_in[4];
    const float* wv  = (const float*)d_in[5];
    const float* bv  = (const float*)d_in[6];
    const float* wo  = (const float*)d_in[7];
    const float* bo  = (const float*)d_in[8];
    const float* w1  = (const float*)d_in[9];
    const float* b1  = (const float*)d_in[10];
    const float* w2  = (const float*)d_in[11];
    const float* b2  = (const float*)d_in[12];
    const float* g1  = (const float*)d_in[13];
    const float* be1 = (const float*)d_in[14];
    const float* g2  = (const float*)d_in[15];
    const float* be2 = (const float*)d_in[16];
    float* out = (float*)d_out;

    char* ws = (char*)d_ws;
    const size_t MB = 1ull << 20;
    bf16_t* xb    = (bf16_t*)(ws + 0);        //  8MB; reused as ab after attention
    bf16_t* WtQKV = (bf16_t*)(ws + 8 * MB);   //  6MB [q|k|v][1024] rows x 1024
    bf16_t* WtO   = (bf16_t*)(ws + 14 * MB);  //  2MB
    bf16_t* Wt1   = (bf16_t*)(ws + 16 * MB);  //  8MB
    bf16_t* Wt2   = (bf16_t*)(ws + 24 * MB);  //  8MB
    float*  bqkv  = (float*)(ws + 32 * MB);   //  8KB (bq|bk)
    bf16_t* QKb   = (bf16_t*)(ws + 33 * MB);  // 16MB [4096][2048] (dead after attn)
    bf16_t* Vt    = (bf16_t*)(ws + 49 * MB);  //  8MB [2][1024][2048] (dead after attn)
    bf16_t* ffb   = (bf16_t*)(ws + 33 * MB);  // 32MB overlays QKb+Vt
    float*  oa    = (float*)(ws + 65 * MB);   // 32MB: 2 partials (dead after LN1)
    float*  f2    = (float*)(ws + 65 * MB);   // 32MB: 2 partials, overlays oa
    float*  hbuf  = (float*)(ws + 97 * MB);   // 16MB
    bf16_t* hb    = (bf16_t*)(ws + 113 * MB); //  8MB
    bf16_t* ab    = xb;
    const int MN = 4096 * 1024;
    const float Cs = 0.125f * 1.4426950408889634f;  // softmax scale * log2(e)

    // 1. prep
    PrepArgs pa;
    pa.w[0] = wq; pa.w[1] = wk; pa.w[2] = wv; pa.w[3] = wo; pa.w[4] = w1; pa.w[5] = w2;
    pa.wt[0] = WtQKV; pa.wt[1] = WtQKV + 1024 * 1024; pa.wt[2] = WtQKV + 2048 * 1024;
    pa.wt[3] = WtO; pa.wt[4] = Wt1; pa.wt[5] = Wt2;
    int Ksz[6] = {1024, 1024, 1024, 1024, 1024, 4096};
    int Nsz[6] = {1024, 1024, 1024, 1024, 4096, 1024};
    int st[6]  = {0, 1024, 2048, 3072, 4096, 8192};
    for (int i = 0; i < 6; i++) { pa.K[i] = Ksz[i]; pa.N[i] = Nsz[i]; pa.start[i] = st[i]; }
    pa.x = x; pa.xb = xb; pa.castStart = 12288;
    pa.bq = bq; pa.bk = bk; pa.bqkv = bqkv; pa.biasStart = 12288 + 4096;
    prep<<<12288 + 4096 + 1, 256, 0, stream>>>(pa);

    // 2. merged QK-proj + V-proj (one launch, 768 blocks)
    GemmDesc dqk = { xb, WtQKV, bqkv, nullptr, QKb,
                     4096, 2048, 1024, 1024, 0, 16, 0, 0, 0, 1024, Cs };
    GemmDesc dv  = { WtQKV + 2048 * 1024, xb, bv, nullptr, Vt,
                     1024, 2048, 1024, 1024, 0, 16, 1,
                     (long)2048 * 1024, (long)1024 * 2048, 0, 1.f };
    gemm_dual<<<768, 256, 0, stream>>>(dqk, 512, dv, 128);

    // 3. flash attention (128-row Q tiles, 8 waves) -> ab (= xb, dead)
    flash_attn_mfma<<<dim3(16, 16, 2), 512, 0, stream>>>(QKb, Vt, ab);

    // 4. Wo projection, split-K=2 -> partials oa[0],oa[1]
    GemmDesc dwo = { ab, WtO, bo, oa, nullptr,
                     4096, 1024, 1024, 512, 0, 8, 0, 0, 0, 0, 1.f };
    gemm_bt<4><<<dim3(256, 1, 2), 256, 0, stream>>>(dwo);

    // 5. h = LN(x + oa0 + oa1)
    resid_ln3<<<4096, 256, 0, stream>>>(x, oa, oa + MN, g1, be1, hbuf, hb);

    // 6. FF1 + relu -> ffb bf16
    GemmDesc df1 = { hb, Wt1, b1, nullptr, ffb,
                     4096, 4096, 1024, 1024, 1, 32, 0, 0, 0, 0, 1.f };
    gemm_bt<4><<<1024, 256, 0, stream>>>(df1);

    // 7. FF2, split-K=2 -> partials f2[0],f2[1]
    GemmDesc df2 = { ffb, Wt2, b2, f2, nullptr,
                     4096, 1024, 4096, 2048, 0, 8, 0, 0, 0, 0, 1.f };
    gemm_bt<4><<<dim3(256, 1, 2), 256, 0, stream>>>(df2);

    // 8. out = LN(h + f2_0 + f2_1)
    resid_ln3<<<4096, 256, 0, stream>>>(hbuf, f2, f2 + MN, g2, be2, out, nullptr);
}

// Round 8
// 414.278 us; speedup vs baseline: 1.0106x; 1.0106x over previous
//
#include <hip/hip_runtime.h>
#include <hip/hip_bf16.h>
#include <cmath>

typedef __bf16 bf16_t;
typedef __bf16 bf16x4 __attribute__((ext_vector_type(4)));
typedef __bf16 bf16x8 __attribute__((ext_vector_type(8)));
typedef float  f32x4  __attribute__((ext_vector_type(4)));

// ---------------------------------------------------------------------------
// async global->LDS, 16B per lane (used by attention staging only; the GEMM
// now uses register-staged pipelining — see gemm_core r8 notes)
// ---------------------------------------------------------------------------
__device__ __forceinline__ void gld_lds16(const bf16_t* g, bf16_t* l) {
    __builtin_amdgcn_global_load_lds(
        (const __attribute__((address_space(1))) void*)g,
        (__attribute__((address_space(3))) void*)l,
        16, 0, 0);
}

// ---------------------------------------------------------------------------
// prep: ONE launch for x-cast + 6 weight transposes + qk-bias pack
// ---------------------------------------------------------------------------
struct PrepArgs {
    const float* w[6]; bf16_t* wt[6];
    int K[6], N[6], start[6];
    const float* x; bf16_t* xb; int castStart;
    const float* bq; const float* bk; float* bqkv; int biasStart;
};

__global__ __launch_bounds__(256) void prep(PrepArgs pa) {
    __shared__ float tile[32][33];
    const int bid = blockIdx.x, t = threadIdx.x;
    if (bid < pa.castStart) {
        int mi = 0;
#pragma unroll
        for (int i = 1; i < 6; i++) if (bid >= pa.start[i]) mi = i;
        const int tt  = bid - pa.start[mi];
        const int nbx = pa.N[mi] >> 5;
        const int n0 = (tt % nbx) * 32, k0 = (tt / nbx) * 32;
        const float* in = pa.w[mi];
        bf16_t* out = pa.wt[mi];
        const int K = pa.K[mi], N = pa.N[mi];
        const int tx = t & 31, ty = t >> 5;
#pragma unroll
        for (int i = 0; i < 4; i++) {
            int kk = ty + i * 8;
            tile[kk][tx] = in[(size_t)(k0 + kk) * N + n0 + tx];
        }
        __syncthreads();
#pragma unroll
        for (int i = 0; i < 4; i++) {
            int nn = ty + i * 8;
            out[(size_t)(n0 + nn) * K + k0 + tx] = (bf16_t)tile[tx][nn];
        }
    } else if (bid < pa.biasStart) {
        int i = (bid - pa.castStart) * 256 + t;
        f32x4 v = ((const f32x4*)pa.x)[i];
        bf16x4 o;
        o[0] = (bf16_t)v[0]; o[1] = (bf16_t)v[1]; o[2] = (bf16_t)v[2]; o[3] = (bf16_t)v[3];
        ((bf16x4*)pa.xb)[i] = o;
    } else {
#pragma unroll
        for (int j = 0; j < 8; j++) {
            int idx = t * 8 + j;
            pa.bqkv[idx] = idx < 1024 ? pa.bq[idx] : pa.bk[idx - 1024];
        }
    }
}

// ---------------------------------------------------------------------------
// GEMM descriptor + core:  C[M][N] = A[M][K]*Bt[N][K]^T + bias (+relu)
// Tile (MT*32)x128, BK=64 as two 32-halves, 4 waves (2x2).
// r8: REGISTER-STAGED PIPELINE. global_load_lds forces a vmcnt(0) drain at
// every barrier (LDS-writing loads must be visible) -> all co-resident
// blocks stall in lockstep for full HBM latency each K-iter (measured:
// MfmaUtil == single-block timeline, 18.5%). Instead: issue plain
// global_load_dwordx4 -> VGPR for tile k+1 BEFORE computing tile k; the
// vmcnt wait attaches to the ds_write (first use) a full compute-phase
// later, and plain VGPR loads need no drain at barriers.
// ---------------------------------------------------------------------------
struct GemmDesc {
    const bf16_t* A; const bf16_t* Bt; const float* bias;
    float* Cf; bf16_t* Cb;
    int M, N, lda, Kloc, relu, nbn, bias_row;
    long bt_bstride, c_bstride;
    int scale_cols; float scale;
};

template<int MT>
__device__ __forceinline__ void gemm_core(const GemmDesc& d, int bidx, int batch,
                                          int kh, bf16_t* As, bf16_t* Bs) {
    constexpr int TM = MT * 32;
    const int tid  = threadIdx.x;
    const int lane = tid & 63;
    const int wave = tid >> 6;
    const int wm = wave & 1, wn = wave >> 1;

    const int span  = 8 * d.nbn;            // nbm % 8 == 0 for all launches
    const int group = bidx / span;
    const int rem   = bidx % span;
    const int bm    = group * 8 + (rem & 7);
    const int bn    = rem >> 3;

    const bf16_t* Bt_b = d.Bt + (size_t)batch * d.bt_bstride;
    float*  Cf_b = d.Cf ? d.Cf + (size_t)batch * d.c_bstride + (size_t)kh * d.M * d.N : nullptr;
    bf16_t* Cb_b = d.Cb ? d.Cb + (size_t)batch * d.c_bstride : nullptr;
    const int koff = kh * d.Kloc;

    const int r4 = tid >> 2;
    const int kc = (tid & 3) * 8;
    const bf16_t* Ag = d.A  + (size_t)(bm * TM  + r4) * d.lda + koff + kc;
    const bf16_t* Bg = Bt_b + (size_t)(bn * 128 + r4) * d.lda + koff + kc;

    f32x4 acc[MT][4] = {};
    const int mrow = lane & 15;
    const int q8   = (lane >> 4) * 8;

    // prefetch registers: tile k+1 lives here while tile k computes
    bf16x8 pA[MT / 2][2], pB[2][2];

#define LOAD_TILE(K0)                                                          \
    {                                                                          \
        _Pragma("unroll")                                                      \
        for (int hh = 0; hh < 2; hh++) {                                       \
            _Pragma("unroll")                                                  \
            for (int i = 0; i < MT / 2; i++)                                   \
                pA[i][hh] = *(const bf16x8*)(Ag + (size_t)(i * 64) * d.lda +   \
                                             (K0) + hh * 32);                  \
            pB[0][hh] = *(const bf16x8*)(Bg + (K0) + hh * 32);                 \
            pB[1][hh] = *(const bf16x8*)(Bg + (size_t)64 * d.lda + (K0) + hh * 32); \
        }                                                                      \
    }
#define STORE_TILE()                                                           \
    {                                                                          \
        _Pragma("unroll")                                                      \
        for (int hh = 0; hh < 2; hh++) {                                       \
            _Pragma("unroll")                                                  \
            for (int i = 0; i < MT / 2; i++)                                   \
                *(bf16x8*)(As + hh * (TM * 32) + i * 64 * 32 + tid * 8) = pA[i][hh]; \
            *(bf16x8*)(Bs + hh * 4096 + tid * 8) = pB[0][hh];                  \
            *(bf16x8*)(Bs + hh * 4096 + 64 * 32 + tid * 8) = pB[1][hh];        \
        }                                                                      \
    }

    LOAD_TILE(0);
    STORE_TILE();                       // vmcnt wait here (prologue only)

    for (int k0 = 0; k0 < d.Kloc; k0 += 64) {
        __syncthreads();                // LDS writes visible before reads
        const bool more = (k0 + 64 < d.Kloc);
        if (more) LOAD_TILE(k0 + 64);   // in flight during compute

#pragma unroll
        for (int hh = 0; hh < 2; hh++) {
            bf16x8 af[MT], bfr[4];
#pragma unroll
            for (int mt = 0; mt < MT; mt++)
                af[mt] = *(const bf16x8*)(As + hh * (TM * 32) +
                                          (wm * (MT * 16) + mt * 16 + mrow) * 32 + q8);
#pragma unroll
            for (int nt = 0; nt < 4; nt++)
                bfr[nt] = *(const bf16x8*)(Bs + hh * 4096 +
                                           (wn * 64 + nt * 16 + mrow) * 32 + q8);
#pragma unroll
            for (int mt = 0; mt < MT; mt++)
#pragma unroll
                for (int nt = 0; nt < 4; nt++)
                    acc[mt][nt] = __builtin_amdgcn_mfma_f32_16x16x32_bf16(
                        af[mt], bfr[nt], acc[mt][nt], 0, 0, 0);
        }

        __syncthreads();                // all reads done before overwrite
        if (more) STORE_TILE();         // vmcnt wait: loads issued 1 iter ago
    }
#undef LOAD_TILE
#undef STORE_TILE

    const int rq = (lane >> 4) * 4;
#pragma unroll
    for (int mt = 0; mt < MT; mt++) {
        int row0 = bm * TM + wm * (MT * 16) + mt * 16 + rq;
#pragma unroll
        for (int nt = 0; nt < 4; nt++) {
            int col = bn * 128 + wn * 64 + nt * 16 + mrow;
            float bvc = (d.bias && kh == 0 && !d.bias_row) ? d.bias[col] : 0.f;
            float sc = (col < d.scale_cols) ? d.scale : 1.f;
#pragma unroll
            for (int r = 0; r < 4; r++) {
                float bb = (d.bias && kh == 0 && d.bias_row) ? d.bias[row0 + r] : bvc;
                float v = acc[mt][nt][r] + bb;
                if (d.relu) v = fmaxf(v, 0.f);
                v *= sc;
                size_t idx = (size_t)(row0 + r) * d.N + col;
                if (Cf_b) Cf_b[idx] = v;
                if (Cb_b) Cb_b[idx] = (bf16_t)v;
            }
        }
    }
}

template<int MT>
__global__ __launch_bounds__(256) void gemm_bt(GemmDesc d) {
    __shared__ __attribute__((aligned(16))) bf16_t As[2 * MT * 32 * 32];
    __shared__ __attribute__((aligned(16))) bf16_t Bs[2 * 128 * 32];
    gemm_core<MT>(d, blockIdx.x, blockIdx.y, blockIdx.z, As, Bs);
}

// Two independent MT=4 GEMMs in one launch (overlaps ramps).
__global__ __launch_bounds__(256) void gemm_dual(GemmDesc d0, int nblocks0,
                                                 GemmDesc d1, int nblocks1) {
    __shared__ __attribute__((aligned(16))) bf16_t As[2 * 128 * 32];
    __shared__ __attribute__((aligned(16))) bf16_t Bs[2 * 128 * 32];
    const int bid = blockIdx.x;
    if (bid < nblocks0) {
        gemm_core<4>(d0, bid, 0, 0, As, Bs);
    } else {
        int b2 = bid - nblocks0;
        gemm_core<4>(d1, b2 % nblocks1, b2 / nblocks1, 0, As, Bs);
    }
}

// ---------------------------------------------------------------------------
// MFMA flash attention (bf16, no-max softmax, MFMA row-sum).
// 128-row Q tile, 8 waves. QKb [B*S][2048]: q (pre-scaled by 0.125*log2e)
// at h*64, k at 1024+h*64. Vt [B][1024][2048]: row hd, col s.
// ---------------------------------------------------------------------------
__global__ __launch_bounds__(512) void flash_attn_mfma(
    const bf16_t* __restrict__ QKb,
    const bf16_t* __restrict__ Vtg,
    bf16_t* __restrict__ Outb) {
    __shared__ __attribute__((aligned(16))) bf16_t QPs[128 * 72];
    __shared__ __attribute__((aligned(16))) bf16_t Ks[2][64 * 32];
    __shared__ __attribute__((aligned(16))) bf16_t Vs[2][64 * 32];
    const int t = threadIdx.x;
    const int lane = t & 63, wave = t >> 6;
    const int g = lane >> 4, cl = lane & 15;
    const int b = blockIdx.z, h = blockIdx.y, q0 = blockIdx.x * 128;
    const int RS = 2048;
    const bf16_t* Qg = QKb + (size_t)(b * 2048 + q0) * RS + h * 64;
    const bf16_t* Kg = QKb + (size_t)(b * 2048) * RS + 1024 + h * 64;
    const bf16_t* Vg = Vtg + ((size_t)b * 1024 + h * 64) * 2048;

    {
        int qr = t >> 2, qc = (t & 3) * 8;
        gld_lds16(Qg + (size_t)qr * RS + qc,      QPs + t * 8);
        gld_lds16(Qg + (size_t)qr * RS + 32 + qc, QPs + 4096 + t * 8);
    }
    const int kr = (t & 255) >> 2;
    const int kc = (t & 3) * 8;
    const int khf = (t >> 8) * 32;

    f32x4 Oacc[4] = {};
    f32x4 Lacc = {};
    bf16x8 ones;
#pragma unroll
    for (int j = 0; j < 8; j++) ones[j] = (bf16_t)1.0f;

    const int qrow_s = (wave * 16 + cl) * 32 + g * 8;
    const int prow_w = (wave * 16 + cl) * 72;

    __syncthreads();
    const bf16x8 bq0 = *(const bf16x8*)(QPs + qrow_s);
    const bf16x8 bq1 = *(const bf16x8*)(QPs + 4096 + qrow_s);

    for (int kt = 0; kt < 2048; kt += 64) {
        __syncthreads();
        gld_lds16(Kg + (size_t)(kt + kr) * RS + khf + kc,  (bf16_t*)Ks + t * 8);
        gld_lds16(Vg + (size_t)kr * 2048 + kt + khf + kc,  (bf16_t*)Vs + t * 8);
        __syncthreads();

        f32x4 Sacc[4] = {};
#pragma unroll
        for (int ks = 0; ks < 2; ks++) {
            const bf16x8 bq = ks ? bq1 : bq0;
#pragma unroll
            for (int mt = 0; mt < 4; mt++) {
                bf16x8 ak = *(const bf16x8*)(&Ks[ks][(mt * 16 + cl) * 32 + g * 8]);
                Sacc[mt] = __builtin_amdgcn_mfma_f32_16x16x32_bf16(ak, bq, Sacc[mt], 0, 0, 0);
            }
        }

#pragma unroll
        for (int mt = 0; mt < 4; mt++) {
            bf16x4 p4;
#pragma unroll
            for (int r = 0; r < 4; r++)
                p4[r] = (bf16_t)__builtin_amdgcn_exp2f(Sacc[mt][r]);
            *(bf16x4*)(QPs + prow_w + mt * 16 + g * 4) = p4;
        }

#pragma unroll
        for (int ks = 0; ks < 2; ks++) {
            bf16x8 ap = *(const bf16x8*)(QPs + prow_w + ks * 32 + g * 8);
            Lacc = __builtin_amdgcn_mfma_f32_16x16x32_bf16(ap, ones, Lacc, 0, 0, 0);
#pragma unroll
            for (int nt = 0; nt < 4; nt++) {
                bf16x8 bv = *(const bf16x8*)(&Vs[ks][(nt * 16 + cl) * 32 + g * 8]);
                Oacc[nt] = __builtin_amdgcn_mfma_f32_16x16x32_bf16(ap, bv, Oacc[nt], 0, 0, 0);
            }
        }
    }

#pragma unroll
    for (int r = 0; r < 4; r++) {
        float inv = 1.f / Lacc[r];
        int qrow = q0 + wave * 16 + g * 4 + r;
        size_t base = (size_t)(b * 2048 + qrow) * 1024 + h * 64;
#pragma unroll
        for (int nt = 0; nt < 4; nt++)
            Outb[base + nt * 16 + cl] = (bf16_t)(Oacc[nt][r] * inv);
    }
}

// ---------------------------------------------------------------------------
// out = LN(a + p0 + p1) * g + be ; p1/outb nullable. one block/row, D=1024
// ---------------------------------------------------------------------------
__global__ __launch_bounds__(256) void resid_ln3(const float* __restrict__ a,
                                                 const float* __restrict__ p0,
                                                 const float* __restrict__ p1,
                                                 const float* __restrict__ g,
                                                 const float* __restrict__ be,
                                                 float* __restrict__ outf,
                                                 bf16_t* __restrict__ outb) {
    const int row = blockIdx.x, t = threadIdx.x;
    const size_t base = (size_t)row * 1024;
    f32x4 v = ((const f32x4*)(a + base))[t] + ((const f32x4*)(p0 + base))[t];
    if (p1) v += ((const f32x4*)(p1 + base))[t];
    float sum = v[0] + v[1] + v[2] + v[3];
    float sq  = v[0] * v[0] + v[1] * v[1] + v[2] * v[2] + v[3] * v[3];
#pragma unroll
    for (int o = 1; o < 64; o <<= 1) {
        sum += __shfl_xor(sum, o);
        sq  += __shfl_xor(sq, o);
    }
    __shared__ float red[8];
    int wave = t >> 6, lane = t & 63;
    if (lane == 0) { red[wave] = sum; red[4 + wave] = sq; }
    __syncthreads();
    sum = red[0] + red[1] + red[2] + red[3];
    sq  = red[4] + red[5] + red[6] + red[7];
    float mu  = sum * (1.f / 1024.f);
    float var = sq * (1.f / 1024.f) - mu * mu;
    float rs  = rsqrtf(var + 1e-6f);
    f32x4 g4 = ((const f32x4*)g)[t];
    f32x4 b4 = ((const f32x4*)be)[t];
    f32x4 o = (v - mu) * rs * g4 + b4;
    ((f32x4*)(outf + base))[t] = o;
    if (outb) {
        bf16x4 ob;
        ob[0] = (bf16_t)o[0]; ob[1] = (bf16_t)o[1]; ob[2] = (bf16_t)o[2]; ob[3] = (bf16_t)o[3];
        ((bf16x4*)(outb + base))[t] = ob;
    }
}

// ---------------------------------------------------------------------------
extern "C" void kernel_launch(void* const* d_in, const int* in_sizes, int n_in,
                              void* d_out, int out_size, void* d_ws, size_t ws_size,
                              hipStream_t stream) {
    (void)in_sizes; (void)n_in; (void)out_size; (void)ws_size;
    const float* x   = (const float*)d_in[0];
    const float* wq  = (const float*)d_in[1];
    const float* bq  = (const float*)d_in[2];
    const float* wk  = (const float*)d_in[3];
    const float* bk  = (const float*)d_in[4];
    const float* wv  = (const float*)d_in[5];
    const float* bv  = (const float*)d_in[6];
    const float* wo  = (const float*)d_in[7];
    const float* bo  = (const float*)d_in[8];
    const float* w1  = (const float*)d_in[9];
    const float* b1  = (const float*)d_in[10];
    const float* w2  = (const float*)d_in[11];
    const float* b2  = (const float*)d_in[12];
    const float* g1  = (const float*)d_in[13];
    const float* be1 = (const float*)d_in[14];
    const float* g2  = (const float*)d_in[15];
    const float* be2 = (const float*)d_in[16];
    float* out = (float*)d_out;

    char* ws = (char*)d_ws;
    const size_t MB = 1ull << 20;
    bf16_t* xb    = (bf16_t*)(ws + 0);        //  8MB; reused as ab after attention
    bf16_t* WtQKV = (bf16_t*)(ws + 8 * MB);   //  6MB [q|k|v][1024] rows x 1024
    bf16_t* WtO   = (bf16_t*)(ws + 14 * MB);  //  2MB
    bf16_t* Wt1   = (bf16_t*)(ws + 16 * MB);  //  8MB
    bf16_t* Wt2   = (bf16_t*)(ws + 24 * MB);  //  8MB
    float*  bqkv  = (float*)(ws + 32 * MB);   //  8KB (bq|bk)
    bf16_t* QKb   = (bf16_t*)(ws + 33 * MB);  // 16MB [4096][2048] (dead after attn)
    bf16_t* Vt    = (bf16_t*)(ws + 49 * MB);  //  8MB [2][1024][2048] (dead after attn)
    bf16_t* ffb   = (bf16_t*)(ws + 33 * MB);  // 32MB overlays QKb+Vt
    float*  oa    = (float*)(ws + 65 * MB);   // 32MB: 2 partials (dead after LN1)
    float*  f2    = (float*)(ws + 65 * MB);   // 32MB: 2 partials, overlays oa
    float*  hbuf  = (float*)(ws + 97 * MB);   // 16MB
    bf16_t* hb    = (bf16_t*)(ws + 113 * MB); //  8MB
    bf16_t* ab    = xb;
    const int MN = 4096 * 1024;
    const float Cs = 0.125f * 1.4426950408889634f;  // softmax scale * log2(e)

    // 1. prep
    PrepArgs pa;
    pa.w[0] = wq; pa.w[1] = wk; pa.w[2] = wv; pa.w[3] = wo; pa.w[4] = w1; pa.w[5] = w2;
    pa.wt[0] = WtQKV; pa.wt[1] = WtQKV + 1024 * 1024; pa.wt[2] = WtQKV + 2048 * 1024;
    pa.wt[3] = WtO; pa.wt[4] = Wt1; pa.wt[5] = Wt2;
    int Ksz[6] = {1024, 1024, 1024, 1024, 1024, 4096};
    int Nsz[6] = {1024, 1024, 1024, 1024, 4096, 1024};
    int st[6]  = {0, 1024, 2048, 3072, 4096, 8192};
    for (int i = 0; i < 6; i++) { pa.K[i] = Ksz[i]; pa.N[i] = Nsz[i]; pa.start[i] = st[i]; }
    pa.x = x; pa.xb = xb; pa.castStart = 12288;
    pa.bq = bq; pa.bk = bk; pa.bqkv = bqkv; pa.biasStart = 12288 + 4096;
    prep<<<12288 + 4096 + 1, 256, 0, stream>>>(pa);

    // 2. merged QK-proj + V-proj (one launch, 768 blocks)
    GemmDesc dqk = { xb, WtQKV, bqkv, nullptr, QKb,
                     4096, 2048, 1024, 1024, 0, 16, 0, 0, 0, 1024, Cs };
    GemmDesc dv  = { WtQKV + 2048 * 1024, xb, bv, nullptr, Vt,
                     1024, 2048, 1024, 1024, 0, 16, 1,
                     (long)2048 * 1024, (long)1024 * 2048, 0, 1.f };
    gemm_dual<<<768, 256, 0, stream>>>(dqk, 512, dv, 128);

    // 3. flash attention (128-row Q tiles, 8 waves) -> ab (= xb, dead)
    flash_attn_mfma<<<dim3(16, 16, 2), 512, 0, stream>>>(QKb, Vt, ab);

    // 4. Wo projection, split-K=2 -> partials oa[0],oa[1]
    GemmDesc dwo = { ab, WtO, bo, oa, nullptr,
                     4096, 1024, 1024, 512, 0, 8, 0, 0, 0, 0, 1.f };
    gemm_bt<4><<<dim3(256, 1, 2), 256, 0, stream>>>(dwo);

    // 5. h = LN(x + oa0 + oa1)
    resid_ln3<<<4096, 256, 0, stream>>>(x, oa, oa + MN, g1, be1, hbuf, hb);

    // 6. FF1 + relu -> ffb bf16
    GemmDesc df1 = { hb, Wt1, b1, nullptr, ffb,
                     4096, 4096, 1024, 1024, 1, 32, 0, 0, 0, 0, 1.f };
    gemm_bt<4><<<1024, 256, 0, stream>>>(df1);

    // 7. FF2, split-K=2 -> partials f2[0],f2[1]
    GemmDesc df2 = { ffb, Wt2, b2, f2, nullptr,
                     4096, 1024, 4096, 2048, 0, 8, 0, 0, 0, 0, 1.f };
    gemm_bt<4><<<dim3(256, 1, 2), 256, 0, stream>>>(df2);

    // 8. out = LN(h + f2_0 + f2_1)
    resid_ln3<<<4096, 256, 0, stream>>>(hbuf, f2, f2 + MN, g2, be2, out, nullptr);
}